// Round 14
// baseline (543.512 us; speedup 1.0000x reference)
//
#include <hip/hip_runtime.h>
#include <hip/hip_bf16.h>

#define NN 50000
#define NE 800000
#define D 128
#define ED 64
#define IN_DIM 320
#define MB 64            // edges per tile
#define KP 328           // padded LDS row (ushorts)
#define NT (NE / MB)     // 12500 tiles
#define PGRID 512        // 2 blocks/CU * 256 CU — tripwire-passing config
#define NB ((NN + 255) / 256)   // 196 scan blocks

typedef short short8 __attribute__((ext_vector_type(8)));
typedef float f32x4 __attribute__((ext_vector_type(4)));

__device__ __forceinline__ ushort f2b(float f) {
  __hip_bfloat16 h = __float2bfloat16(f);
  return *reinterpret_cast<ushort*>(&h);
}
__device__ __forceinline__ float b2f(ushort u) {
  return __uint_as_float(((uint)u) << 16);
}
__device__ __forceinline__ ushort4 c4(float4 v) {
  ushort4 u; u.x = f2b(v.x); u.y = f2b(v.y); u.z = f2b(v.z); u.w = f2b(v.w);
  return u;
}

// row gathers with PRE-RESOLVED indices (no dependent index loads here):
// 4 threads per edge, 20 x ushort4 per thread.
__device__ __forceinline__ void gather_rows(
    ushort4 g[20], int sidx, int ridx, int ge,
    const float* __restrict__ nodes, const float* __restrict__ efeat, int p)
{
  const float* ns = nodes + (size_t)sidx * D;
  const float* nr = nodes + (size_t)ridx * D;
  const float* ef = efeat + (size_t)ge * ED;
#pragma unroll
  for (int i = 0; i < 8; ++i) g[i] = c4(*(const float4*)(ns + (p + 4 * i) * 4));
#pragma unroll
  for (int i = 0; i < 8; ++i) g[8 + i] = c4(*(const float4*)(nr + (p + 4 * i) * 4));
#pragma unroll
  for (int i = 0; i < 4; ++i) g[16 + i] = c4(*(const float4*)(ef + (p + 4 * i) * 4));
}

__device__ __forceinline__ void write_xs(
    ushort xs[MB][KP], const ushort4 g[20], int tid)
{
  const int e = tid >> 2, p = tid & 3;
#pragma unroll
  for (int i = 0; i < 8; ++i)
    *reinterpret_cast<ushort4*>(&xs[e][(p + 4 * i) * 4]) = g[i];
#pragma unroll
  for (int i = 0; i < 8; ++i)
    *reinterpret_cast<ushort4*>(&xs[e][128 + (p + 4 * i) * 4]) = g[8 + i];
#pragma unroll
  for (int i = 0; i < 4; ++i)
    *reinterpret_cast<ushort4*>(&xs[e][256 + (p + 4 * i) * 4]) = g[16 + i];
}

// ---------------- weight transpose + bf16 convert ---------------------------
__global__ __launch_bounds__(256) void k_wconv(
    const float* __restrict__ Wq, const float* __restrict__ W1,
    ushort* __restrict__ Wqt, ushort* __restrict__ W1t)
{
  int i = blockIdx.x * 256 + threadIdx.x;
  if (i < D * IN_DIM) {
    int n = i / IN_DIM, k = i - n * IN_DIM;
    Wqt[i] = f2b(Wq[k * D + n]);
    W1t[i] = f2b(W1[k * D + n]);
  }
}

// ---------------- pass 1: queries (bf16,+bq) + logits + seg_max -------------
// Bucket-order processing (R13) with a 2-tile-deep index pipeline: the
// ebuf->senders/receivers chain is resolved two tiles ahead, so steady-state
// row gathers have ZERO dependent loads (R13's 375us vs R12's 344us gap was
// exactly this chain). Epilogue receiver is prefetched at tile top too.
__global__ __launch_bounds__(256, 2) void k_fused(
    const float* __restrict__ nodes,
    const int* __restrict__ senders, const int* __restrict__ receivers,
    const float* __restrict__ efeat, const int* __restrict__ ebuf,
    const ushort* __restrict__ Wqt, const float* __restrict__ bq,
    const ushort* __restrict__ W1t, const float* __restrict__ b1,
    const float* __restrict__ gamma_, const float* __restrict__ beta_,
    const float* __restrict__ W2, const float* __restrict__ b2,
    ushort* __restrict__ queries, float* __restrict__ logits,
    float* __restrict__ seg_max)
{
  __shared__ ushort xs[MB][KP];
  __shared__ float red[MB][4][3];
  const int tid = threadIdx.x;
  const int w = tid >> 6, l = tid & 63, lr = l & 15, lg = l >> 4;
  const int n0 = 32 * w + lr, n1 = 32 * w + 16 + lr;
  const int le = tid >> 2, lp = tid & 3;

  const float b1a = b1[n0], b1b = b1[n1];
  const float g0 = gamma_[n0], g1 = gamma_[n1];
  const float be0 = beta_[n0], be1 = beta_[n1];
  const float w20 = W2[n0], w21 = W2[n1];
  const float bq0 = bq[n0], bq1 = bq[n1];
  const float b2s = b2[0];
  const float wg0 = w20 * g0, wg1 = w21 * g1;

  // tile-invariant: S1=sum(w2*g), B2t=sum(w2*beta)+b2 (0.25: cols counted 4x)
  {
    float p1 = wg0 + wg1;
    float p2 = w20 * be0 + w21 * be1;
#pragma unroll
    for (int off = 1; off < 64; off <<= 1) {
      p1 += __shfl_xor(p1, off);
      p2 += __shfl_xor(p2, off);
    }
    if (l == 0) { red[0][w][0] = p1; red[0][w][1] = p2; }
  }
  __syncthreads();
  const float S1  = 0.25f * (red[0][0][0] + red[0][1][0] + red[0][2][0] + red[0][3][0]);
  const float B2t = 0.25f * (red[0][0][1] + red[0][1][1] + red[0][2][1] + red[0][3][1]) + b2s;

  int tile = blockIdx.x;
  ushort4 g[20];
  int sidx = 0, ridx = 0, gea = 0;   // resolved indices for tile+PGRID
  {
    // prologue: tile's rows (serial chain once), tile+PGRID's indices
    int ge0 = ebuf[tile * MB + le];
    int s0 = senders[ge0], r0 = receivers[ge0];
    gather_rows(g, s0, r0, ge0, nodes, efeat, lp);
    int t1 = tile + PGRID;
    if (t1 < NT) {
      gea = ebuf[t1 * MB + le];
      sidx = senders[gea];
      ridx = receivers[gea];
    }
  }

  while (tile < NT) {
    const int e0 = tile * MB;
    // top prefetches (independent of xs; latency covered by q-GEMM):
    const int t2 = tile + 2 * PGRID;
    int geC = 0;
    if (t2 < NT) geC = ebuf[t2 * MB + le];
    int rr = 0;
    if (tid < MB) rr = receivers[ebuf[e0 + tid]];

    write_xs(xs, g, tid);
    __syncthreads();                                   // (A) xs ready

    // q-GEMM: Wq streamed from L2
    f32x4 aq[4][2] = {};
#pragma unroll 2
    for (int ks = 0; ks < 10; ++ks) {
      short8 Q0 = *reinterpret_cast<const short8*>(Wqt + n0 * IN_DIM + ks * 32 + lg * 8);
      short8 Q1 = *reinterpret_cast<const short8*>(Wqt + n1 * IN_DIM + ks * 32 + lg * 8);
      short8 A[4];
#pragma unroll
      for (int mt = 0; mt < 4; ++mt)
        A[mt] = *reinterpret_cast<const short8*>(&xs[mt * 16 + lr][ks * 32 + lg * 8]);
#pragma unroll
      for (int mt = 0; mt < 4; ++mt) {
        aq[mt][0] = __builtin_amdgcn_mfma_f32_16x16x32_bf16(A[mt], Q0, aq[mt][0], 0, 0, 0);
        aq[mt][1] = __builtin_amdgcn_mfma_f32_16x16x32_bf16(A[mt], Q1, aq[mt][1], 0, 0, 0);
      }
    }
    // store queries (+bq) sequentially at bucket positions
#pragma unroll
    for (int mt = 0; mt < 4; ++mt)
#pragma unroll
      for (int r = 0; r < 4; ++r) {
        int row = mt * 16 + lg * 4 + r;
        queries[(size_t)(e0 + row) * D + n0] = f2b(aq[mt][0][r] + bq0);
        queries[(size_t)(e0 + row) * D + n1] = f2b(aq[mt][1][r] + bq1);
      }

    // row gathers for tile+PGRID — indices fully resolved last iteration
    const int nxt = tile + PGRID;
    if (nxt < NT)
      gather_rows(g, sidx, ridx, gea, nodes, efeat, lp);
    // resolve indices for tile+2*PGRID (geC loaded at tile top, ready now)
    if (t2 < NT) {
      sidx = senders[geC];
      ridx = receivers[geC];
      gea = geC;
    }

    // h-GEMM: W1 streamed
    f32x4 ah[4][2] = {};
#pragma unroll
    for (int ks = 0; ks < 10; ++ks) {
      short8 Y0 = *reinterpret_cast<const short8*>(W1t + n0 * IN_DIM + ks * 32 + lg * 8);
      short8 Y1 = *reinterpret_cast<const short8*>(W1t + n1 * IN_DIM + ks * 32 + lg * 8);
      short8 A[4];
#pragma unroll
      for (int mt = 0; mt < 4; ++mt)
        A[mt] = *reinterpret_cast<const short8*>(&xs[mt * 16 + lr][ks * 32 + lg * 8]);
#pragma unroll
      for (int mt = 0; mt < 4; ++mt) {
        ah[mt][0] = __builtin_amdgcn_mfma_f32_16x16x32_bf16(A[mt], Y0, ah[mt][0], 0, 0, 0);
        ah[mt][1] = __builtin_amdgcn_mfma_f32_16x16x32_bf16(A[mt], Y1, ah[mt][1], 0, 0, 0);
      }
    }

    // relu + fused LN/dot partials (16-lane reduce: each col once per group)
#pragma unroll
    for (int mt = 0; mt < 4; ++mt)
#pragma unroll
      for (int r = 0; r < 4; ++r) {
        float h0 = fmaxf(ah[mt][0][r] + b1a, 0.f);
        float h1 = fmaxf(ah[mt][1][r] + b1b, 0.f);
        float s = h0 + h1;
        float q = h0 * h0 + h1 * h1;
        float t = h0 * wg0 + h1 * wg1;
#pragma unroll
        for (int off = 1; off < 16; off <<= 1) {
          s += __shfl_xor(s, off);
          q += __shfl_xor(q, off);
          t += __shfl_xor(t, off);
        }
        if (lr == mt * 4 + r) {
          int row = mt * 16 + lg * 4 + r;
          red[row][w][0] = s;
          red[row][w][1] = q;
          red[row][w][2] = t;
        }
      }
    __syncthreads();                                   // (B) red ready
    if (tid < MB) {
      float s = red[tid][0][0] + red[tid][1][0] + red[tid][2][0] + red[tid][3][0];
      float q = red[tid][0][1] + red[tid][1][1] + red[tid][2][1] + red[tid][3][1];
      float t = red[tid][0][2] + red[tid][1][2] + red[tid][2][2] + red[tid][3][2];
      float mu = s * (1.f / 128.f);
      float var = fmaxf(q * (1.f / 128.f) - mu * mu, 0.f);
      float rs = rsqrtf(var + 1e-5f);
      float logit = fmaxf(rs * (t - mu * S1) + B2t, 0.f);
      logits[e0 + tid] = logit;                        // bucket position
      atomicMax((int*)&seg_max[rr], __float_as_int(logit));
    }
    tile = nxt;
  }
}

// ---------------- counting sort by receiver ---------------------------------
__global__ __launch_bounds__(256) void k_hist(
    const int* __restrict__ receivers, int* __restrict__ deg)
{
  int e = blockIdx.x * 256 + threadIdx.x;
  if (e < NE) atomicAdd(&deg[receivers[e]], 1);
}

__global__ __launch_bounds__(256) void k_scan1(
    const int* __restrict__ deg, int* __restrict__ bsum)
{
  __shared__ int buf[256];
  int i = blockIdx.x * 256 + threadIdx.x;
  int v = (i < NN) ? deg[i] : 0;
  buf[threadIdx.x] = v;
  __syncthreads();
  for (int off = 128; off > 0; off >>= 1) {
    if (threadIdx.x < off) buf[threadIdx.x] += buf[threadIdx.x + off];
    __syncthreads();
  }
  if (threadIdx.x == 0) bsum[blockIdx.x] = buf[0];
}

__global__ __launch_bounds__(256) void k_scan2(
    const int* __restrict__ bsum, int* __restrict__ bpre, int* __restrict__ offs)
{
  __shared__ int buf[256];
  int t = threadIdx.x;
  int v = (t < NB) ? bsum[t] : 0;
  buf[t] = v;
  __syncthreads();
  for (int off = 1; off < 256; off <<= 1) {
    int x = (t >= off) ? buf[t - off] : 0;
    __syncthreads();
    buf[t] += x;
    __syncthreads();
  }
  if (t < NB) bpre[t] = buf[t] - v;          // exclusive
  if (t == 0) offs[NN] = NE;                  // sentinel
}

__global__ __launch_bounds__(256) void k_scan3(
    const int* __restrict__ deg, const int* __restrict__ bpre,
    int* __restrict__ offs, int* __restrict__ cursor)
{
  __shared__ int buf[256];
  int t = threadIdx.x;
  int i = blockIdx.x * 256 + t;
  int v = (i < NN) ? deg[i] : 0;
  buf[t] = v;
  __syncthreads();
  for (int off = 1; off < 256; off <<= 1) {
    int x = (t >= off) ? buf[t - off] : 0;
    __syncthreads();
    buf[t] += x;
    __syncthreads();
  }
  if (i < NN) {
    int o = bpre[blockIdx.x] + buf[t] - v;
    offs[i] = o;
    cursor[i] = o;
  }
}

__global__ __launch_bounds__(256) void k_bucket(
    const int* __restrict__ receivers, int* __restrict__ cursor,
    int* __restrict__ ebuf)
{
  int e = blockIdx.x * 256 + threadIdx.x;
  if (e < NE) {
    int pos = atomicAdd(&cursor[receivers[e]], 1);
    ebuf[pos] = e;
  }
}

// Canonicalize bucket order (atomicAdd placement is scheduling-dependent):
// insertion-sort each node's segment so ebuf is a pure function of inputs.
__global__ __launch_bounds__(256) void k_bsort(
    const int* __restrict__ offs, int* __restrict__ ebuf)
{
  int node = blockIdx.x * 256 + threadIdx.x;
  if (node >= NN) return;
  const int beg = offs[node], end = offs[node + 1];
  for (int i = beg + 1; i < end; ++i) {
    int v = ebuf[i];
    int j = i - 1;
    while (j >= beg && ebuf[j] > v) { ebuf[j + 1] = ebuf[j]; --j; }
    ebuf[j + 1] = v;
  }
}

// ---------------- gather-side output: fully streaming -----------------------
// queries/logits are bucket-ordered -> rows beg..end contiguous; 4-deep
// batching with strict ascending-i accumulation (tripwire-green in R12/R13).
__global__ __launch_bounds__(256) void k_out(
    const int* __restrict__ offs, const float* __restrict__ logits,
    const float* __restrict__ seg_max, const ushort* __restrict__ queries,
    float* __restrict__ out)
{
  int node = blockIdx.x * 8 + (threadIdx.x >> 5);
  if (node >= NN) return;
  const int cg = (threadIdx.x & 31) * 4;      // 4 columns per lane
  const int beg = offs[node], end = offs[node + 1];
  const float smax = seg_max[node];
  float a0 = 0.f, a1 = 0.f, a2 = 0.f, a3 = 0.f, den = 0.f;

  int i = beg;
  for (; i + 4 <= end; i += 4) {
    float l0 = logits[i], l1 = logits[i + 1], l2 = logits[i + 2], l3 = logits[i + 3];
    ushort4 q0 = *reinterpret_cast<const ushort4*>(queries + (size_t)i * D + cg);
    ushort4 q1 = *reinterpret_cast<const ushort4*>(queries + (size_t)(i + 1) * D + cg);
    ushort4 q2 = *reinterpret_cast<const ushort4*>(queries + (size_t)(i + 2) * D + cg);
    ushort4 q3 = *reinterpret_cast<const ushort4*>(queries + (size_t)(i + 3) * D + cg);
    float x0 = expf(l0 - smax), x1 = expf(l1 - smax);
    float x2 = expf(l2 - smax), x3 = expf(l3 - smax);
    a0 = fmaf(x0, b2f(q0.x), a0); a1 = fmaf(x0, b2f(q0.y), a1);
    a2 = fmaf(x0, b2f(q0.z), a2); a3 = fmaf(x0, b2f(q0.w), a3); den += x0;
    a0 = fmaf(x1, b2f(q1.x), a0); a1 = fmaf(x1, b2f(q1.y), a1);
    a2 = fmaf(x1, b2f(q1.z), a2); a3 = fmaf(x1, b2f(q1.w), a3); den += x1;
    a0 = fmaf(x2, b2f(q2.x), a0); a1 = fmaf(x2, b2f(q2.y), a1);
    a2 = fmaf(x2, b2f(q2.z), a2); a3 = fmaf(x2, b2f(q2.w), a3); den += x2;
    a0 = fmaf(x3, b2f(q3.x), a0); a1 = fmaf(x3, b2f(q3.y), a1);
    a2 = fmaf(x3, b2f(q3.z), a2); a3 = fmaf(x3, b2f(q3.w), a3); den += x3;
  }
  for (; i < end; ++i) {
    float ex = expf(logits[i] - smax);
    ushort4 q = *reinterpret_cast<const ushort4*>(queries + (size_t)i * D + cg);
    a0 = fmaf(ex, b2f(q.x), a0); a1 = fmaf(ex, b2f(q.y), a1);
    a2 = fmaf(ex, b2f(q.z), a2); a3 = fmaf(ex, b2f(q.w), a3);
    den += ex;
  }

  float inv = 1.f / (den + 1e-10f);
  float4 v;
  v.x = a0 * inv; v.y = a1 * inv; v.z = a2 * inv; v.w = a3 * inv;
  v.x = v.x > 0.f ? v.x : 0.01f * v.x;
  v.y = v.y > 0.f ? v.y : 0.01f * v.y;
  v.z = v.z > 0.f ? v.z : 0.01f * v.z;
  v.w = v.w > 0.f ? v.w : 0.01f * v.w;
  *reinterpret_cast<float4*>(out + (size_t)node * D + cg) = v;
}

extern "C" void kernel_launch(void* const* d_in, const int* in_sizes, int n_in,
                              void* d_out, int out_size, void* d_ws, size_t ws_size,
                              hipStream_t stream) {
  const float* nodes  = (const float*)d_in[0];
  const int*   eidx   = (const int*)d_in[1];
  const float* efeat  = (const float*)d_in[2];
  const float* Wq     = (const float*)d_in[3];
  const float* bq     = (const float*)d_in[4];
  const float* W1     = (const float*)d_in[5];
  const float* b1     = (const float*)d_in[6];
  const float* gamma_ = (const float*)d_in[7];
  const float* beta_  = (const float*)d_in[8];
  const float* W2     = (const float*)d_in[9];
  const float* b2     = (const float*)d_in[10];
  const int* senders   = eidx;
  const int* receivers = eidx + NE;

  // ws layout (pad before ebuf keeps Wqt/W1t/queries 16B-aligned)
  float* ws       = (float*)d_ws;
  float* logits   = ws;                      // NE f32 (bucket-ordered)
  float* seg_max  = ws + NE;                 // NN f32
  int*   deg      = (int*)(seg_max + NN);    // NN
  int*   offs     = deg + NN;                // NN+1
  int*   cursor   = offs + NN + 1;           // NN
  int*   bsum     = cursor + NN;             // 256
  int*   bpre     = bsum + 256;              // 256
  int*   ebuf     = bpre + 256 + 3;          // NE
  ushort* Wqt     = (ushort*)(ebuf + NE);    // 128*320, 16B-aligned
  ushort* W1t     = Wqt + D * IN_DIM;        // 128*320, 16B-aligned
  ushort* queries = W1t + D * IN_DIM;        // NE*128 bf16 (bucket-ordered)

  hipMemsetAsync(seg_max, 0, NN * sizeof(float), stream);
  hipMemsetAsync(deg, 0, NN * sizeof(int), stream);

  k_wconv<<<(D * IN_DIM + 255) / 256, 256, 0, stream>>>(Wq, W1, Wqt, W1t);

  // counting sort + canonical order (must precede k_fused: it reads ebuf)
  k_hist<<<(NE + 255) / 256, 256, 0, stream>>>(receivers, deg);
  k_scan1<<<NB, 256, 0, stream>>>(deg, bsum);
  k_scan2<<<1, 256, 0, stream>>>(bsum, bpre, offs);
  k_scan3<<<NB, 256, 0, stream>>>(deg, bpre, offs, cursor);
  k_bucket<<<(NE + 255) / 256, 256, 0, stream>>>(receivers, cursor, ebuf);
  k_bsort<<<NB, 256, 0, stream>>>(offs, ebuf);

  // queries + logits (bucket-ordered) + seg_max
  k_fused<<<PGRID, 256, 0, stream>>>(nodes, senders, receivers, efeat, ebuf,
                                     Wqt, bq, W1t, b1, gamma_, beta_, W2, b2,
                                     queries, logits, seg_max);

  // gather-side softmax + weighted sum + leaky relu (fully streaming)
  k_out<<<(NN + 7) / 8, 256, 0, stream>>>(offs, logits, seg_max,
                                          queries, (float*)d_out);
}

// Round 15
// 491.189 us; speedup vs baseline: 1.1065x; 1.1065x over previous
//
#include <hip/hip_runtime.h>
#include <hip/hip_bf16.h>

#define NN 50000
#define NE 800000
#define D 128
#define ED 64
#define IN_DIM 320
#define MB 64            // edges per tile
#define KP 328           // padded LDS row (ushorts)
#define NT (NE / MB)     // 12500 tiles
#define PGRID 512        // 2 blocks/CU * 256 CU — tripwire-passing config
#define NB ((NN + 255) / 256)   // 196 scan blocks

typedef short short8 __attribute__((ext_vector_type(8)));
typedef float f32x4 __attribute__((ext_vector_type(4)));

__device__ __forceinline__ ushort f2b(float f) {
  __hip_bfloat16 h = __float2bfloat16(f);
  return *reinterpret_cast<ushort*>(&h);
}
__device__ __forceinline__ float b2f(ushort u) {
  return __uint_as_float(((uint)u) << 16);
}
__device__ __forceinline__ ushort4 c4(float4 v) {
  ushort4 u; u.x = f2b(v.x); u.y = f2b(v.y); u.z = f2b(v.z); u.w = f2b(v.w);
  return u;
}

// gather one tile's x into bf16 registers; node rows read from the
// PRE-CONVERTED bf16 table (256B/row instead of 512B — half the random
// gather traffic, zero conversion VALU); efeat converted in-flight.
// 4 threads per edge, 20 x ushort4.
__device__ __forceinline__ void gather_regs(
    ushort4 g[20], const int* __restrict__ senders,
    const int* __restrict__ receivers, const ushort* __restrict__ nodesb,
    const float* __restrict__ efeat, int e0, int tid)
{
  const int e = tid >> 2, p = tid & 3;
  const ushort* ns = nodesb + (size_t)senders[e0 + e] * D;
  const ushort* nr = nodesb + (size_t)receivers[e0 + e] * D;
  const float* ef = efeat + (size_t)(e0 + e) * ED;
#pragma unroll
  for (int i = 0; i < 8; ++i)
    g[i] = *(const ushort4*)(ns + (p + 4 * i) * 4);
#pragma unroll
  for (int i = 0; i < 8; ++i)
    g[8 + i] = *(const ushort4*)(nr + (p + 4 * i) * 4);
#pragma unroll
  for (int i = 0; i < 4; ++i)
    g[16 + i] = c4(*(const float4*)(ef + (p + 4 * i) * 4));
}

__device__ __forceinline__ void write_xs(
    ushort xs[MB][KP], const ushort4 g[20], int tid)
{
  const int e = tid >> 2, p = tid & 3;
#pragma unroll
  for (int i = 0; i < 8; ++i)
    *reinterpret_cast<ushort4*>(&xs[e][(p + 4 * i) * 4]) = g[i];
#pragma unroll
  for (int i = 0; i < 8; ++i)
    *reinterpret_cast<ushort4*>(&xs[e][128 + (p + 4 * i) * 4]) = g[8 + i];
#pragma unroll
  for (int i = 0; i < 4; ++i)
    *reinterpret_cast<ushort4*>(&xs[e][256 + (p + 4 * i) * 4]) = g[16 + i];
}

// ---------------- weight transpose + bf16 convert ---------------------------
__global__ __launch_bounds__(256) void k_wconv(
    const float* __restrict__ Wq, const float* __restrict__ W1,
    ushort* __restrict__ Wqt, ushort* __restrict__ W1t)
{
  int i = blockIdx.x * 256 + threadIdx.x;
  if (i < D * IN_DIM) {
    int n = i / IN_DIM, k = i - n * IN_DIM;
    Wqt[i] = f2b(Wq[k * D + n]);
    W1t[i] = f2b(W1[k * D + n]);
  }
}

// ---------------- nodes f32 -> bf16 table (same rounding as old in-gather
// conversion -> bit-identical downstream results) -----------------------------
__global__ __launch_bounds__(256) void k_nconv(
    const float* __restrict__ nodes, ushort* __restrict__ nodesb)
{
  int i = blockIdx.x * 256 + threadIdx.x;     // over NN*D/4
  if (i < NN * D / 4) {
    float4 v = *reinterpret_cast<const float4*>(nodes + (size_t)i * 4);
    *reinterpret_cast<ushort4*>(nodesb + (size_t)i * 4) = c4(v);
  }
}

// ---------------- pass 1: queries (bf16,+bq) + logits + seg_max -------------
// R12 structure (344us, tripwire-green), gathering from the bf16 node table.
__global__ __launch_bounds__(256, 2) void k_fused(
    const ushort* __restrict__ nodesb,
    const int* __restrict__ senders, const int* __restrict__ receivers,
    const float* __restrict__ efeat,
    const ushort* __restrict__ Wqt, const float* __restrict__ bq,
    const ushort* __restrict__ W1t, const float* __restrict__ b1,
    const float* __restrict__ gamma_, const float* __restrict__ beta_,
    const float* __restrict__ W2, const float* __restrict__ b2,
    ushort* __restrict__ queries, float* __restrict__ logits,
    float* __restrict__ seg_max)
{
  __shared__ ushort xs[MB][KP];
  __shared__ float red[MB][4][3];
  const int tid = threadIdx.x;
  const int w = tid >> 6, l = tid & 63, lr = l & 15, lg = l >> 4;
  const int n0 = 32 * w + lr, n1 = 32 * w + 16 + lr;

  const float b1a = b1[n0], b1b = b1[n1];
  const float g0 = gamma_[n0], g1 = gamma_[n1];
  const float be0 = beta_[n0], be1 = beta_[n1];
  const float w20 = W2[n0], w21 = W2[n1];
  const float bq0 = bq[n0], bq1 = bq[n1];
  const float b2s = b2[0];
  const float wg0 = w20 * g0, wg1 = w21 * g1;

  // tile-invariant: S1=sum(w2*g), B2t=sum(w2*beta)+b2 (0.25: cols counted 4x)
  {
    float p1 = wg0 + wg1;
    float p2 = w20 * be0 + w21 * be1;
#pragma unroll
    for (int off = 1; off < 64; off <<= 1) {
      p1 += __shfl_xor(p1, off);
      p2 += __shfl_xor(p2, off);
    }
    if (l == 0) { red[0][w][0] = p1; red[0][w][1] = p2; }
  }
  __syncthreads();
  const float S1  = 0.25f * (red[0][0][0] + red[0][1][0] + red[0][2][0] + red[0][3][0]);
  const float B2t = 0.25f * (red[0][0][1] + red[0][1][1] + red[0][2][1] + red[0][3][1]) + b2s;

  int tile = blockIdx.x;
  ushort4 g[20];
  gather_regs(g, senders, receivers, nodesb, efeat, tile * MB, tid);

  while (tile < NT) {
    const int e0 = tile * MB;
    write_xs(xs, g, tid);
    __syncthreads();                                   // (A) xs ready

    // q-GEMM: Wq streamed from L2 (issued BEFORE prefetch gathers)
    f32x4 aq[4][2] = {};
#pragma unroll 2
    for (int ks = 0; ks < 10; ++ks) {
      short8 Q0 = *reinterpret_cast<const short8*>(Wqt + n0 * IN_DIM + ks * 32 + lg * 8);
      short8 Q1 = *reinterpret_cast<const short8*>(Wqt + n1 * IN_DIM + ks * 32 + lg * 8);
      short8 A[4];
#pragma unroll
      for (int mt = 0; mt < 4; ++mt)
        A[mt] = *reinterpret_cast<const short8*>(&xs[mt * 16 + lr][ks * 32 + lg * 8]);
#pragma unroll
      for (int mt = 0; mt < 4; ++mt) {
        aq[mt][0] = __builtin_amdgcn_mfma_f32_16x16x32_bf16(A[mt], Q0, aq[mt][0], 0, 0, 0);
        aq[mt][1] = __builtin_amdgcn_mfma_f32_16x16x32_bf16(A[mt], Q1, aq[mt][1], 0, 0, 0);
      }
    }
#pragma unroll
    for (int mt = 0; mt < 4; ++mt)
#pragma unroll
      for (int r = 0; r < 4; ++r) {
        int row = mt * 16 + lg * 4 + r;
        queries[(size_t)(e0 + row) * D + n0] = f2b(aq[mt][0][r] + bq0);
        queries[(size_t)(e0 + row) * D + n1] = f2b(aq[mt][1][r] + bq1);
      }

    // prefetch next tile's gathers
    const int nxt = tile + PGRID;
    if (nxt < NT)
      gather_regs(g, senders, receivers, nodesb, efeat, nxt * MB, tid);

    // h-GEMM: W1 streamed
    f32x4 ah[4][2] = {};
#pragma unroll
    for (int ks = 0; ks < 10; ++ks) {
      short8 Y0 = *reinterpret_cast<const short8*>(W1t + n0 * IN_DIM + ks * 32 + lg * 8);
      short8 Y1 = *reinterpret_cast<const short8*>(W1t + n1 * IN_DIM + ks * 32 + lg * 8);
      short8 A[4];
#pragma unroll
      for (int mt = 0; mt < 4; ++mt)
        A[mt] = *reinterpret_cast<const short8*>(&xs[mt * 16 + lr][ks * 32 + lg * 8]);
#pragma unroll
      for (int mt = 0; mt < 4; ++mt) {
        ah[mt][0] = __builtin_amdgcn_mfma_f32_16x16x32_bf16(A[mt], Y0, ah[mt][0], 0, 0, 0);
        ah[mt][1] = __builtin_amdgcn_mfma_f32_16x16x32_bf16(A[mt], Y1, ah[mt][1], 0, 0, 0);
      }
    }

    // relu + fused LN/dot partials (16-lane reduce: each col once per group)
#pragma unroll
    for (int mt = 0; mt < 4; ++mt)
#pragma unroll
      for (int r = 0; r < 4; ++r) {
        float h0 = fmaxf(ah[mt][0][r] + b1a, 0.f);
        float h1 = fmaxf(ah[mt][1][r] + b1b, 0.f);
        float s = h0 + h1;
        float q = h0 * h0 + h1 * h1;
        float t = h0 * wg0 + h1 * wg1;
#pragma unroll
        for (int off = 1; off < 16; off <<= 1) {
          s += __shfl_xor(s, off);
          q += __shfl_xor(q, off);
          t += __shfl_xor(t, off);
        }
        if (lr == mt * 4 + r) {
          int row = mt * 16 + lg * 4 + r;
          red[row][w][0] = s;
          red[row][w][1] = q;
          red[row][w][2] = t;
        }
      }
    __syncthreads();                                   // (B) red ready
    if (tid < MB) {
      float s = red[tid][0][0] + red[tid][1][0] + red[tid][2][0] + red[tid][3][0];
      float q = red[tid][0][1] + red[tid][1][1] + red[tid][2][1] + red[tid][3][1];
      float t = red[tid][0][2] + red[tid][1][2] + red[tid][2][2] + red[tid][3][2];
      float mu = s * (1.f / 128.f);
      float var = fmaxf(q * (1.f / 128.f) - mu * mu, 0.f);
      float rs = rsqrtf(var + 1e-5f);
      float logit = fmaxf(rs * (t - mu * S1) + B2t, 0.f);
      logits[e0 + tid] = logit;
      atomicMax((int*)&seg_max[receivers[e0 + tid]], __float_as_int(logit));
    }
    tile = nxt;
  }
}

// ---------------- counting sort by receiver ---------------------------------
__global__ __launch_bounds__(256) void k_hist(
    const int* __restrict__ receivers, int* __restrict__ deg)
{
  int e = blockIdx.x * 256 + threadIdx.x;
  if (e < NE) atomicAdd(&deg[receivers[e]], 1);
}

__global__ __launch_bounds__(256) void k_scan1(
    const int* __restrict__ deg, int* __restrict__ bsum)
{
  __shared__ int buf[256];
  int i = blockIdx.x * 256 + threadIdx.x;
  int v = (i < NN) ? deg[i] : 0;
  buf[threadIdx.x] = v;
  __syncthreads();
  for (int off = 128; off > 0; off >>= 1) {
    if (threadIdx.x < off) buf[threadIdx.x] += buf[threadIdx.x + off];
    __syncthreads();
  }
  if (threadIdx.x == 0) bsum[blockIdx.x] = buf[0];
}

__global__ __launch_bounds__(256) void k_scan2(
    const int* __restrict__ bsum, int* __restrict__ bpre, int* __restrict__ offs)
{
  __shared__ int buf[256];
  int t = threadIdx.x;
  int v = (t < NB) ? bsum[t] : 0;
  buf[t] = v;
  __syncthreads();
  for (int off = 1; off < 256; off <<= 1) {
    int x = (t >= off) ? buf[t - off] : 0;
    __syncthreads();
    buf[t] += x;
    __syncthreads();
  }
  if (t < NB) bpre[t] = buf[t] - v;          // exclusive
  if (t == 0) offs[NN] = NE;                  // sentinel
}

__global__ __launch_bounds__(256) void k_scan3(
    const int* __restrict__ deg, const int* __restrict__ bpre,
    int* __restrict__ offs, int* __restrict__ cursor)
{
  __shared__ int buf[256];
  int t = threadIdx.x;
  int i = blockIdx.x * 256 + t;
  int v = (i < NN) ? deg[i] : 0;
  buf[t] = v;
  __syncthreads();
  for (int off = 1; off < 256; off <<= 1) {
    int x = (t >= off) ? buf[t - off] : 0;
    __syncthreads();
    buf[t] += x;
    __syncthreads();
  }
  if (i < NN) {
    int o = bpre[blockIdx.x] + buf[t] - v;
    offs[i] = o;
    cursor[i] = o;
  }
}

__global__ __launch_bounds__(256) void k_bucket(
    const int* __restrict__ receivers, int* __restrict__ cursor,
    int* __restrict__ ebuf)
{
  int e = blockIdx.x * 256 + threadIdx.x;
  if (e < NE) {
    int pos = atomicAdd(&cursor[receivers[e]], 1);
    ebuf[pos] = e;
  }
}

// Canonicalize bucket order (atomicAdd placement is scheduling-dependent):
// insertion-sort each node's segment so ebuf is a pure function of inputs.
__global__ __launch_bounds__(256) void k_bsort(
    const int* __restrict__ offs, int* __restrict__ ebuf)
{
  int node = blockIdx.x * 256 + threadIdx.x;
  if (node >= NN) return;
  const int beg = offs[node], end = offs[node + 1];
  for (int i = beg + 1; i < end; ++i) {
    int v = ebuf[i];
    int j = i - 1;
    while (j >= beg && ebuf[j] > v) { ebuf[j + 1] = ebuf[j]; --j; }
    ebuf[j + 1] = v;
  }
}

// ---------------- gather-side output ----------------------------------------
// R12 version (tripwire-green): 2 nodes/wave, 4-deep load batching, strict
// ascending-i accumulation per column.
__global__ __launch_bounds__(256) void k_out(
    const int* __restrict__ offs, const int* __restrict__ ebuf,
    const float* __restrict__ logits, const float* __restrict__ seg_max,
    const ushort* __restrict__ queries, float* __restrict__ out)
{
  int node = blockIdx.x * 8 + (threadIdx.x >> 5);
  if (node >= NN) return;
  const int cg = (threadIdx.x & 31) * 4;      // 4 columns per lane
  const int beg = offs[node], end = offs[node + 1];
  const float smax = seg_max[node];
  float a0 = 0.f, a1 = 0.f, a2 = 0.f, a3 = 0.f, den = 0.f;

  int i = beg;
  for (; i + 4 <= end; i += 4) {
    int e0 = ebuf[i], e1 = ebuf[i + 1], e2 = ebuf[i + 2], e3 = ebuf[i + 3];
    float l0 = logits[e0], l1 = logits[e1], l2 = logits[e2], l3 = logits[e3];
    ushort4 q0 = *reinterpret_cast<const ushort4*>(queries + (size_t)e0 * D + cg);
    ushort4 q1 = *reinterpret_cast<const ushort4*>(queries + (size_t)e1 * D + cg);
    ushort4 q2 = *reinterpret_cast<const ushort4*>(queries + (size_t)e2 * D + cg);
    ushort4 q3 = *reinterpret_cast<const ushort4*>(queries + (size_t)e3 * D + cg);
    float x0 = expf(l0 - smax), x1 = expf(l1 - smax);
    float x2 = expf(l2 - smax), x3 = expf(l3 - smax);
    a0 = fmaf(x0, b2f(q0.x), a0); a1 = fmaf(x0, b2f(q0.y), a1);
    a2 = fmaf(x0, b2f(q0.z), a2); a3 = fmaf(x0, b2f(q0.w), a3); den += x0;
    a0 = fmaf(x1, b2f(q1.x), a0); a1 = fmaf(x1, b2f(q1.y), a1);
    a2 = fmaf(x1, b2f(q1.z), a2); a3 = fmaf(x1, b2f(q1.w), a3); den += x1;
    a0 = fmaf(x2, b2f(q2.x), a0); a1 = fmaf(x2, b2f(q2.y), a1);
    a2 = fmaf(x2, b2f(q2.z), a2); a3 = fmaf(x2, b2f(q2.w), a3); den += x2;
    a0 = fmaf(x3, b2f(q3.x), a0); a1 = fmaf(x3, b2f(q3.y), a1);
    a2 = fmaf(x3, b2f(q3.z), a2); a3 = fmaf(x3, b2f(q3.w), a3); den += x3;
  }
  for (; i < end; ++i) {
    int e = ebuf[i];
    float ex = expf(logits[e] - smax);
    ushort4 q = *reinterpret_cast<const ushort4*>(queries + (size_t)e * D + cg);
    a0 = fmaf(ex, b2f(q.x), a0); a1 = fmaf(ex, b2f(q.y), a1);
    a2 = fmaf(ex, b2f(q.z), a2); a3 = fmaf(ex, b2f(q.w), a3);
    den += ex;
  }

  float inv = 1.f / (den + 1e-10f);
  float4 v;
  v.x = a0 * inv; v.y = a1 * inv; v.z = a2 * inv; v.w = a3 * inv;
  v.x = v.x > 0.f ? v.x : 0.01f * v.x;
  v.y = v.y > 0.f ? v.y : 0.01f * v.y;
  v.z = v.z > 0.f ? v.z : 0.01f * v.z;
  v.w = v.w > 0.f ? v.w : 0.01f * v.w;
  *reinterpret_cast<float4*>(out + (size_t)node * D + cg) = v;
}

extern "C" void kernel_launch(void* const* d_in, const int* in_sizes, int n_in,
                              void* d_out, int out_size, void* d_ws, size_t ws_size,
                              hipStream_t stream) {
  const float* nodes  = (const float*)d_in[0];
  const int*   eidx   = (const int*)d_in[1];
  const float* efeat  = (const float*)d_in[2];
  const float* Wq     = (const float*)d_in[3];
  const float* bq     = (const float*)d_in[4];
  const float* W1     = (const float*)d_in[5];
  const float* b1     = (const float*)d_in[6];
  const float* gamma_ = (const float*)d_in[7];
  const float* beta_  = (const float*)d_in[8];
  const float* W2     = (const float*)d_in[9];
  const float* b2     = (const float*)d_in[10];
  const int* senders   = eidx;
  const int* receivers = eidx + NE;

  // ws layout (pad before ebuf keeps nodesb/Wqt/W1t/queries 16B-aligned)
  float* ws       = (float*)d_ws;
  float* logits   = ws;                      // NE f32
  float* seg_max  = ws + NE;                 // NN f32
  int*   deg      = (int*)(seg_max + NN);    // NN
  int*   offs     = deg + NN;                // NN+1
  int*   cursor   = offs + NN + 1;           // NN
  int*   bsum     = cursor + NN;             // 256
  int*   bpre     = bsum + 256;              // 256
  int*   ebuf     = bpre + 256 + 3;          // NE
  ushort* nodesb  = (ushort*)(ebuf + NE);    // NN*128 bf16, 16B-aligned
  ushort* Wqt     = nodesb + (size_t)NN * D; // 128*320
  ushort* W1t     = Wqt + D * IN_DIM;        // 128*320
  ushort* queries = W1t + D * IN_DIM;        // NE*128 bf16

  hipMemsetAsync(seg_max, 0, NN * sizeof(float), stream);
  hipMemsetAsync(deg, 0, NN * sizeof(int), stream);

  k_wconv<<<(D * IN_DIM + 255) / 256, 256, 0, stream>>>(Wq, W1, Wqt, W1t);
  k_nconv<<<(NN * D / 4 + 255) / 256, 256, 0, stream>>>(nodes, nodesb);

  // counting sort + canonical order
  k_hist<<<(NE + 255) / 256, 256, 0, stream>>>(receivers, deg);
  k_scan1<<<NB, 256, 0, stream>>>(deg, bsum);
  k_scan2<<<1, 256, 0, stream>>>(bsum, bpre, offs);
  k_scan3<<<NB, 256, 0, stream>>>(deg, bpre, offs, cursor);
  k_bucket<<<(NE + 255) / 256, 256, 0, stream>>>(receivers, cursor, ebuf);
  k_bsort<<<NB, 256, 0, stream>>>(offs, ebuf);

  // queries + logits + seg_max (gathers from bf16 node table)
  k_fused<<<PGRID, 256, 0, stream>>>(nodesb, senders, receivers, efeat,
                                     Wqt, bq, W1t, b1, gamma_, beta_, W2, b2,
                                     queries, logits, seg_max);

  // gather-side softmax + weighted sum + leaky relu
  k_out<<<(NN + 7) / 8, 256, 0, stream>>>(offs, ebuf, logits, seg_max,
                                          queries, (float*)d_out);
}

// Round 16
// 489.967 us; speedup vs baseline: 1.1093x; 1.0025x over previous
//
#include <hip/hip_runtime.h>
#include <hip/hip_bf16.h>

#define NN 50000
#define NE 800000
#define D 128
#define ED 64
#define IN_DIM 320
#define MB 64            // edges per tile
#define KP 328           // padded LDS row (ushorts)
#define NT (NE / MB)     // 12500 tiles
#define PGRID 512        // 2 blocks/CU * 256 CU — tripwire-passing config
#define NB ((NN + 255) / 256)   // 196 scan blocks

typedef short short8 __attribute__((ext_vector_type(8)));
typedef float f32x4 __attribute__((ext_vector_type(4)));

__device__ __forceinline__ ushort f2b(float f) {
  __hip_bfloat16 h = __float2bfloat16(f);
  return *reinterpret_cast<ushort*>(&h);
}
__device__ __forceinline__ float b2f(ushort u) {
  return __uint_as_float(((uint)u) << 16);
}
__device__ __forceinline__ ushort4 c4(float4 v) {
  ushort4 u; u.x = f2b(v.x); u.y = f2b(v.y); u.z = f2b(v.z); u.w = f2b(v.w);
  return u;
}

// gather one tile's x into bf16 registers; node rows from the bf16 table
// (256B/row), efeat converted in-flight. 4 threads per edge, 20 x ushort4.
__device__ __forceinline__ void gather_regs(
    ushort4 g[20], const int* __restrict__ senders,
    const int* __restrict__ receivers, const ushort* __restrict__ nodesb,
    const float* __restrict__ efeat, int e0, int tid)
{
  const int e = tid >> 2, p = tid & 3;
  const ushort* ns = nodesb + (size_t)senders[e0 + e] * D;
  const ushort* nr = nodesb + (size_t)receivers[e0 + e] * D;
  const float* ef = efeat + (size_t)(e0 + e) * ED;
#pragma unroll
  for (int i = 0; i < 8; ++i)
    g[i] = *(const ushort4*)(ns + (p + 4 * i) * 4);
#pragma unroll
  for (int i = 0; i < 8; ++i)
    g[8 + i] = *(const ushort4*)(nr + (p + 4 * i) * 4);
#pragma unroll
  for (int i = 0; i < 4; ++i)
    g[16 + i] = c4(*(const float4*)(ef + (p + 4 * i) * 4));
}

__device__ __forceinline__ void write_xs(
    ushort xs[MB][KP], const ushort4 g[20], int tid)
{
  const int e = tid >> 2, p = tid & 3;
#pragma unroll
  for (int i = 0; i < 8; ++i)
    *reinterpret_cast<ushort4*>(&xs[e][(p + 4 * i) * 4]) = g[i];
#pragma unroll
  for (int i = 0; i < 8; ++i)
    *reinterpret_cast<ushort4*>(&xs[e][128 + (p + 4 * i) * 4]) = g[8 + i];
#pragma unroll
  for (int i = 0; i < 4; ++i)
    *reinterpret_cast<ushort4*>(&xs[e][256 + (p + 4 * i) * 4]) = g[16 + i];
}

// ---------------- weight transpose + bf16 convert ---------------------------
__global__ __launch_bounds__(256) void k_wconv(
    const float* __restrict__ Wq, const float* __restrict__ W1,
    ushort* __restrict__ Wqt, ushort* __restrict__ W1t)
{
  int i = blockIdx.x * 256 + threadIdx.x;
  if (i < D * IN_DIM) {
    int n = i / IN_DIM, k = i - n * IN_DIM;
    Wqt[i] = f2b(Wq[k * D + n]);
    W1t[i] = f2b(W1[k * D + n]);
  }
}

// ---------------- nodes f32 -> bf16 table ------------------------------------
__global__ __launch_bounds__(256) void k_nconv(
    const float* __restrict__ nodes, ushort* __restrict__ nodesb)
{
  int i = blockIdx.x * 256 + threadIdx.x;     // over NN*D/4
  if (i < NN * D / 4) {
    float4 v = *reinterpret_cast<const float4*>(nodes + (size_t)i * 4);
    *reinterpret_cast<ushort4*>(nodesb + (size_t)i * 4) = c4(v);
  }
}

// ---------------- pass 1: queries (bf16,+bq) + logits + seg_max -------------
// R15 structure, one change: the prefetch gather is issued AFTER the h-GEMM's
// weight loads. vmcnt retires in ISSUE order, so when the gather sat between
// the GEMMs, every h-GEMM weight consume had to drain all 20 gather loads
// (~900cy L3) first — the gather was on the critical path each tile. Now the
// gather's cover is the partials (pure VALU, ~800cy) + epilogue + next-tile
// write_xs wait, and no weight consume waits behind a gather.
__global__ __launch_bounds__(256, 2) void k_fused(
    const ushort* __restrict__ nodesb,
    const int* __restrict__ senders, const int* __restrict__ receivers,
    const float* __restrict__ efeat,
    const ushort* __restrict__ Wqt, const float* __restrict__ bq,
    const ushort* __restrict__ W1t, const float* __restrict__ b1,
    const float* __restrict__ gamma_, const float* __restrict__ beta_,
    const float* __restrict__ W2, const float* __restrict__ b2,
    ushort* __restrict__ queries, float* __restrict__ logits,
    float* __restrict__ seg_max)
{
  __shared__ ushort xs[MB][KP];
  __shared__ float red[MB][4][3];
  const int tid = threadIdx.x;
  const int w = tid >> 6, l = tid & 63, lr = l & 15, lg = l >> 4;
  const int n0 = 32 * w + lr, n1 = 32 * w + 16 + lr;

  const float b1a = b1[n0], b1b = b1[n1];
  const float g0 = gamma_[n0], g1 = gamma_[n1];
  const float be0 = beta_[n0], be1 = beta_[n1];
  const float w20 = W2[n0], w21 = W2[n1];
  const float bq0 = bq[n0], bq1 = bq[n1];
  const float b2s = b2[0];
  const float wg0 = w20 * g0, wg1 = w21 * g1;

  // tile-invariant: S1=sum(w2*g), B2t=sum(w2*beta)+b2 (0.25: cols counted 4x)
  {
    float p1 = wg0 + wg1;
    float p2 = w20 * be0 + w21 * be1;
#pragma unroll
    for (int off = 1; off < 64; off <<= 1) {
      p1 += __shfl_xor(p1, off);
      p2 += __shfl_xor(p2, off);
    }
    if (l == 0) { red[0][w][0] = p1; red[0][w][1] = p2; }
  }
  __syncthreads();
  const float S1  = 0.25f * (red[0][0][0] + red[0][1][0] + red[0][2][0] + red[0][3][0]);
  const float B2t = 0.25f * (red[0][0][1] + red[0][1][1] + red[0][2][1] + red[0][3][1]) + b2s;

  int tile = blockIdx.x;
  ushort4 g[20];
  gather_regs(g, senders, receivers, nodesb, efeat, tile * MB, tid);

  while (tile < NT) {
    const int e0 = tile * MB;
    write_xs(xs, g, tid);
    __syncthreads();                                   // (A) xs ready

    // q-GEMM: Wq streamed from L2
    f32x4 aq[4][2] = {};
#pragma unroll 2
    for (int ks = 0; ks < 10; ++ks) {
      short8 Q0 = *reinterpret_cast<const short8*>(Wqt + n0 * IN_DIM + ks * 32 + lg * 8);
      short8 Q1 = *reinterpret_cast<const short8*>(Wqt + n1 * IN_DIM + ks * 32 + lg * 8);
      short8 A[4];
#pragma unroll
      for (int mt = 0; mt < 4; ++mt)
        A[mt] = *reinterpret_cast<const short8*>(&xs[mt * 16 + lr][ks * 32 + lg * 8]);
#pragma unroll
      for (int mt = 0; mt < 4; ++mt) {
        aq[mt][0] = __builtin_amdgcn_mfma_f32_16x16x32_bf16(A[mt], Q0, aq[mt][0], 0, 0, 0);
        aq[mt][1] = __builtin_amdgcn_mfma_f32_16x16x32_bf16(A[mt], Q1, aq[mt][1], 0, 0, 0);
      }
    }
#pragma unroll
    for (int mt = 0; mt < 4; ++mt)
#pragma unroll
      for (int r = 0; r < 4; ++r) {
        int row = mt * 16 + lg * 4 + r;
        queries[(size_t)(e0 + row) * D + n0] = f2b(aq[mt][0][r] + bq0);
        queries[(size_t)(e0 + row) * D + n1] = f2b(aq[mt][1][r] + bq1);
      }

    // h-GEMM: W1 streamed — all weight loads issued BEFORE the gather
    f32x4 ah[4][2] = {};
#pragma unroll
    for (int ks = 0; ks < 10; ++ks) {
      short8 Y0 = *reinterpret_cast<const short8*>(W1t + n0 * IN_DIM + ks * 32 + lg * 8);
      short8 Y1 = *reinterpret_cast<const short8*>(W1t + n1 * IN_DIM + ks * 32 + lg * 8);
      short8 A[4];
#pragma unroll
      for (int mt = 0; mt < 4; ++mt)
        A[mt] = *reinterpret_cast<const short8*>(&xs[mt * 16 + lr][ks * 32 + lg * 8]);
#pragma unroll
      for (int mt = 0; mt < 4; ++mt) {
        ah[mt][0] = __builtin_amdgcn_mfma_f32_16x16x32_bf16(A[mt], Y0, ah[mt][0], 0, 0, 0);
        ah[mt][1] = __builtin_amdgcn_mfma_f32_16x16x32_bf16(A[mt], Y1, ah[mt][1], 0, 0, 0);
      }
    }

    // prefetch next tile's gathers — covered by partials + epilogue +
    // next-tile write_xs wait; no vmem consume below this point this tile
    const int nxt = tile + PGRID;
    if (nxt < NT)
      gather_regs(g, senders, receivers, nodesb, efeat, nxt * MB, tid);

    // relu + fused LN/dot partials (16-lane reduce: each col once per group)
#pragma unroll
    for (int mt = 0; mt < 4; ++mt)
#pragma unroll
      for (int r = 0; r < 4; ++r) {
        float h0 = fmaxf(ah[mt][0][r] + b1a, 0.f);
        float h1 = fmaxf(ah[mt][1][r] + b1b, 0.f);
        float s = h0 + h1;
        float q = h0 * h0 + h1 * h1;
        float t = h0 * wg0 + h1 * wg1;
#pragma unroll
        for (int off = 1; off < 16; off <<= 1) {
          s += __shfl_xor(s, off);
          q += __shfl_xor(q, off);
          t += __shfl_xor(t, off);
        }
        if (lr == mt * 4 + r) {
          int row = mt * 16 + lg * 4 + r;
          red[row][w][0] = s;
          red[row][w][1] = q;
          red[row][w][2] = t;
        }
      }
    __syncthreads();                                   // (B) red ready
    if (tid < MB) {
      float s = red[tid][0][0] + red[tid][1][0] + red[tid][2][0] + red[tid][3][0];
      float q = red[tid][0][1] + red[tid][1][1] + red[tid][2][1] + red[tid][3][1];
      float t = red[tid][0][2] + red[tid][1][2] + red[tid][2][2] + red[tid][3][2];
      float mu = s * (1.f / 128.f);
      float var = fmaxf(q * (1.f / 128.f) - mu * mu, 0.f);
      float rs = rsqrtf(var + 1e-5f);
      float logit = fmaxf(rs * (t - mu * S1) + B2t, 0.f);
      logits[e0 + tid] = logit;
      atomicMax((int*)&seg_max[receivers[e0 + tid]], __float_as_int(logit));
    }
    tile = nxt;
  }
}

// ---------------- counting sort by receiver ---------------------------------
__global__ __launch_bounds__(256) void k_hist(
    const int* __restrict__ receivers, int* __restrict__ deg)
{
  int e = blockIdx.x * 256 + threadIdx.x;
  if (e < NE) atomicAdd(&deg[receivers[e]], 1);
}

__global__ __launch_bounds__(256) void k_scan1(
    const int* __restrict__ deg, int* __restrict__ bsum)
{
  __shared__ int buf[256];
  int i = blockIdx.x * 256 + threadIdx.x;
  int v = (i < NN) ? deg[i] : 0;
  buf[threadIdx.x] = v;
  __syncthreads();
  for (int off = 128; off > 0; off >>= 1) {
    if (threadIdx.x < off) buf[threadIdx.x] += buf[threadIdx.x + off];
    __syncthreads();
  }
  if (threadIdx.x == 0) bsum[blockIdx.x] = buf[0];
}

__global__ __launch_bounds__(256) void k_scan2(
    const int* __restrict__ bsum, int* __restrict__ bpre, int* __restrict__ offs)
{
  __shared__ int buf[256];
  int t = threadIdx.x;
  int v = (t < NB) ? bsum[t] : 0;
  buf[t] = v;
  __syncthreads();
  for (int off = 1; off < 256; off <<= 1) {
    int x = (t >= off) ? buf[t - off] : 0;
    __syncthreads();
    buf[t] += x;
    __syncthreads();
  }
  if (t < NB) bpre[t] = buf[t] - v;          // exclusive
  if (t == 0) offs[NN] = NE;                  // sentinel
}

__global__ __launch_bounds__(256) void k_scan3(
    const int* __restrict__ deg, const int* __restrict__ bpre,
    int* __restrict__ offs, int* __restrict__ cursor)
{
  __shared__ int buf[256];
  int t = threadIdx.x;
  int i = blockIdx.x * 256 + t;
  int v = (i < NN) ? deg[i] : 0;
  buf[t] = v;
  __syncthreads();
  for (int off = 1; off < 256; off <<= 1) {
    int x = (t >= off) ? buf[t - off] : 0;
    __syncthreads();
    buf[t] += x;
    __syncthreads();
  }
  if (i < NN) {
    int o = bpre[blockIdx.x] + buf[t] - v;
    offs[i] = o;
    cursor[i] = o;
  }
}

__global__ __launch_bounds__(256) void k_bucket(
    const int* __restrict__ receivers, int* __restrict__ cursor,
    int* __restrict__ ebuf)
{
  int e = blockIdx.x * 256 + threadIdx.x;
  if (e < NE) {
    int pos = atomicAdd(&cursor[receivers[e]], 1);
    ebuf[pos] = e;
  }
}

// Canonicalize bucket order (atomicAdd placement is scheduling-dependent):
// insertion-sort each node's segment so ebuf is a pure function of inputs.
__global__ __launch_bounds__(256) void k_bsort(
    const int* __restrict__ offs, int* __restrict__ ebuf)
{
  int node = blockIdx.x * 256 + threadIdx.x;
  if (node >= NN) return;
  const int beg = offs[node], end = offs[node + 1];
  for (int i = beg + 1; i < end; ++i) {
    int v = ebuf[i];
    int j = i - 1;
    while (j >= beg && ebuf[j] > v) { ebuf[j + 1] = ebuf[j]; --j; }
    ebuf[j + 1] = v;
  }
}

// ---------------- gather-side output ----------------------------------------
// R12 version (tripwire-green): 2 nodes/wave, 4-deep load batching, strict
// ascending-i accumulation per column.
__global__ __launch_bounds__(256) void k_out(
    const int* __restrict__ offs, const int* __restrict__ ebuf,
    const float* __restrict__ logits, const float* __restrict__ seg_max,
    const ushort* __restrict__ queries, float* __restrict__ out)
{
  int node = blockIdx.x * 8 + (threadIdx.x >> 5);
  if (node >= NN) return;
  const int cg = (threadIdx.x & 31) * 4;      // 4 columns per lane
  const int beg = offs[node], end = offs[node + 1];
  const float smax = seg_max[node];
  float a0 = 0.f, a1 = 0.f, a2 = 0.f, a3 = 0.f, den = 0.f;

  int i = beg;
  for (; i + 4 <= end; i += 4) {
    int e0 = ebuf[i], e1 = ebuf[i + 1], e2 = ebuf[i + 2], e3 = ebuf[i + 3];
    float l0 = logits[e0], l1 = logits[e1], l2 = logits[e2], l3 = logits[e3];
    ushort4 q0 = *reinterpret_cast<const ushort4*>(queries + (size_t)e0 * D + cg);
    ushort4 q1 = *reinterpret_cast<const ushort4*>(queries + (size_t)e1 * D + cg);
    ushort4 q2 = *reinterpret_cast<const ushort4*>(queries + (size_t)e2 * D + cg);
    ushort4 q3 = *reinterpret_cast<const ushort4*>(queries + (size_t)e3 * D + cg);
    float x0 = expf(l0 - smax), x1 = expf(l1 - smax);
    float x2 = expf(l2 - smax), x3 = expf(l3 - smax);
    a0 = fmaf(x0, b2f(q0.x), a0); a1 = fmaf(x0, b2f(q0.y), a1);
    a2 = fmaf(x0, b2f(q0.z), a2); a3 = fmaf(x0, b2f(q0.w), a3); den += x0;
    a0 = fmaf(x1, b2f(q1.x), a0); a1 = fmaf(x1, b2f(q1.y), a1);
    a2 = fmaf(x1, b2f(q1.z), a2); a3 = fmaf(x1, b2f(q1.w), a3); den += x1;
    a0 = fmaf(x2, b2f(q2.x), a0); a1 = fmaf(x2, b2f(q2.y), a1);
    a2 = fmaf(x2, b2f(q2.z), a2); a3 = fmaf(x2, b2f(q2.w), a3); den += x2;
    a0 = fmaf(x3, b2f(q3.x), a0); a1 = fmaf(x3, b2f(q3.y), a1);
    a2 = fmaf(x3, b2f(q3.z), a2); a3 = fmaf(x3, b2f(q3.w), a3); den += x3;
  }
  for (; i < end; ++i) {
    int e = ebuf[i];
    float ex = expf(logits[e] - smax);
    ushort4 q = *reinterpret_cast<const ushort4*>(queries + (size_t)e * D + cg);
    a0 = fmaf(ex, b2f(q.x), a0); a1 = fmaf(ex, b2f(q.y), a1);
    a2 = fmaf(ex, b2f(q.z), a2); a3 = fmaf(ex, b2f(q.w), a3);
    den += ex;
  }

  float inv = 1.f / (den + 1e-10f);
  float4 v;
  v.x = a0 * inv; v.y = a1 * inv; v.z = a2 * inv; v.w = a3 * inv;
  v.x = v.x > 0.f ? v.x : 0.01f * v.x;
  v.y = v.y > 0.f ? v.y : 0.01f * v.y;
  v.z = v.z > 0.f ? v.z : 0.01f * v.z;
  v.w = v.w > 0.f ? v.w : 0.01f * v.w;
  *reinterpret_cast<float4*>(out + (size_t)node * D + cg) = v;
}

extern "C" void kernel_launch(void* const* d_in, const int* in_sizes, int n_in,
                              void* d_out, int out_size, void* d_ws, size_t ws_size,
                              hipStream_t stream) {
  const float* nodes  = (const float*)d_in[0];
  const int*   eidx   = (const int*)d_in[1];
  const float* efeat  = (const float*)d_in[2];
  const float* Wq     = (const float*)d_in[3];
  const float* bq     = (const float*)d_in[4];
  const float* W1     = (const float*)d_in[5];
  const float* b1     = (const float*)d_in[6];
  const float* gamma_ = (const float*)d_in[7];
  const float* beta_  = (const float*)d_in[8];
  const float* W2     = (const float*)d_in[9];
  const float* b2     = (const float*)d_in[10];
  const int* senders   = eidx;
  const int* receivers = eidx + NE;

  // ws layout (pad before ebuf keeps nodesb/Wqt/W1t/queries 16B-aligned)
  float* ws       = (float*)d_ws;
  float* logits   = ws;                      // NE f32
  float* seg_max  = ws + NE;                 // NN f32
  int*   deg      = (int*)(seg_max + NN);    // NN
  int*   offs     = deg + NN;                // NN+1
  int*   cursor   = offs + NN + 1;           // NN
  int*   bsum     = cursor + NN;             // 256
  int*   bpre     = bsum + 256;              // 256
  int*   ebuf     = bpre + 256 + 3;          // NE
  ushort* nodesb  = (ushort*)(ebuf + NE);    // NN*128 bf16, 16B-aligned
  ushort* Wqt     = nodesb + (size_t)NN * D; // 128*320
  ushort* W1t     = Wqt + D * IN_DIM;        // 128*320
  ushort* queries = W1t + D * IN_DIM;        // NE*128 bf16

  hipMemsetAsync(seg_max, 0, NN * sizeof(float), stream);
  hipMemsetAsync(deg, 0, NN * sizeof(int), stream);

  k_wconv<<<(D * IN_DIM + 255) / 256, 256, 0, stream>>>(Wq, W1, Wqt, W1t);
  k_nconv<<<(NN * D / 4 + 255) / 256, 256, 0, stream>>>(nodes, nodesb);

  // counting sort + canonical order
  k_hist<<<(NE + 255) / 256, 256, 0, stream>>>(receivers, deg);
  k_scan1<<<NB, 256, 0, stream>>>(deg, bsum);
  k_scan2<<<1, 256, 0, stream>>>(bsum, bpre, offs);
  k_scan3<<<NB, 256, 0, stream>>>(deg, bpre, offs, cursor);
  k_bucket<<<(NE + 255) / 256, 256, 0, stream>>>(receivers, cursor, ebuf);
  k_bsort<<<NB, 256, 0, stream>>>(offs, ebuf);

  // queries + logits + seg_max (gathers from bf16 node table)
  k_fused<<<PGRID, 256, 0, stream>>>(nodesb, senders, receivers, efeat,
                                     Wqt, bq, W1t, b1, gamma_, beta_, W2, b2,
                                     queries, logits, seg_max);

  // gather-side softmax + weighted sum + leaky relu
  k_out<<<(NN + 7) / 8, 256, 0, stream>>>(offs, ebuf, logits, seg_max,
                                          queries, (float*)d_out);
}